// Round 10
// baseline (431.674 us; speedup 1.0000x reference)
//
#include <hip/hip_runtime.h>

#define BB 8
#define TIN 168
#define NN 1500
#define TOUTC 24
#define TLEN 162
#define NG 32
#define NTH 1024
#define SN 2
#define TOPKK 12
#define NTILE 94   // ceil(1504/16)
#define NPAD 1504
#define GNPB 4     // nodes per graph block

// workspace offsets (in 4-byte elements)
#define OFF_M1   0
#define OFF_M2   24000
#define OFF_M1T  48000
#define OFF_M2T  72000
#define OFF_EW   96000
#define OFF_EB   96112
#define OFF_ADJ  96128      // fused transposed adj: int2 [13][NN] = {pk_f16(w,w), idx}
#define OFF_FR   135128     // 6 frag planes x 512 ushorts = 1536 floats
#define OFF_PART 328664     // packed f16: 8*32*1500*8 u32 = 3,072,000
// total ws = 3,400,664 floats = 13.6 MB

typedef __attribute__((ext_vector_type(8))) _Float16 half8;
typedef __attribute__((ext_vector_type(4))) _Float16 half4v;
typedef __attribute__((ext_vector_type(2))) _Float16 half2v;
typedef __attribute__((ext_vector_type(4))) float v4f;

// pack 2 f32 -> packed f16 pair in one v_cvt_pkrtz_f16_f32
__device__ __forceinline__ unsigned int pk2(float lo, float hi) {
    return __builtin_bit_cast(unsigned int, __builtin_amdgcn_cvt_pkrtz(lo, hi));
}
__device__ __forceinline__ float h2lo(unsigned int u) {
    return (float)__builtin_bit_cast(half2v, u).x;
}
__device__ __forceinline__ float h2hi(unsigned int u) {
    return (float)__builtin_bit_cast(half2v, u).y;
}
__device__ __forceinline__ half2v as_h2(unsigned int u) { return __builtin_bit_cast(half2v, u); }
__device__ __forceinline__ unsigned int as_u(half2v h) { return __builtin_bit_cast(unsigned int, h); }
__device__ __forceinline__ half8 as_h8(uint4 u) { return __builtin_bit_cast(half8, u); }

// ---------------- prep: embeddings (+transposed copies) + eff. taps + MFMA weight frags ----------------
// frag planes (512 ushorts each):
//  0,1: mat0 = [W1|U] (K=32) hi/lo, A[m=lane&15][k=(lane>>4)*8+j], 8 f16/lane
//  2,3: V2 = 0.64*M2 (K=16) hi/lo, A[m=lane&15][k=(lane>>4)*4+j], 4 f16/lane (16x16x16 frag)
//  4,5: rw1 (K=16) hi/lo, same 4 f16/lane layout
__global__ __launch_bounds__(256) void prep_kernel(
    const float* __restrict__ e1, const float* __restrict__ e2,
    const float* __restrict__ gw1, const float* __restrict__ gb1,
    const float* __restrict__ gw2, const float* __restrict__ gb2,
    const float* __restrict__ pw, const float* __restrict__ pb,
    const float* __restrict__ tw2, const float* __restrict__ tb2,
    const float* __restrict__ tw3, const float* __restrict__ tb3,
    const float* __restrict__ tw6, const float* __restrict__ tb6,
    const float* __restrict__ tw7, const float* __restrict__ tb7,
    const float* __restrict__ mw, const float* __restrict__ rw1,
    float* __restrict__ ws)
{
    int n = blockIdx.x * blockDim.x + threadIdx.x;
    if (n < NN) {
        float a1[16], a2[16];
        #pragma unroll
        for (int o = 0; o < 16; ++o) { a1[o] = gb1[o]; a2[o] = gb2[o]; }
        #pragma unroll
        for (int i = 0; i < 16; ++i) {
            float u = e1[n*16+i], v = e2[n*16+i];
            #pragma unroll
            for (int o = 0; o < 16; ++o) {
                a1[o] += u * gw1[i*16+o];
                a2[o] += v * gw2[i*16+o];
            }
        }
        #pragma unroll
        for (int o = 0; o < 16; ++o) {
            float t1v = tanhf(1.5f*a1[o]);
            float t2v = tanhf(1.5f*a2[o]);
            ws[OFF_M1 + n*16+o] = t1v;
            ws[OFF_M2 + n*16+o] = t2v;
            ws[OFF_M1T + o*NN + n] = t1v;   // transposed: coalesced graph reads
            ws[OFF_M2T + o*NN + n] = t2v;
        }
    }
    if (blockIdx.x == 0 && threadIdx.x < 16) {
        int c = threadIdx.x;
        int br = c >> 2, oc = c & 3;
        const float* tw; const float* tb; int k;
        if (br == 0)      { tw = tw2; tb = tb2; k = 2; }
        else if (br == 1) { tw = tw3; tb = tb3; k = 3; }
        else if (br == 2) { tw = tw6; tb = tb6; k = 6; }
        else              { tw = tw7; tb = tb7; k = 7; }
        for (int d = 0; d < 7; ++d) ws[OFF_EW + c*7 + d] = 0.f;
        float ebv = tb[oc];
        for (int j = 0; j < k; ++j) {
            float s = 0.f, sb = 0.f;
            for (int ic = 0; ic < 16; ++ic) {
                float w = tw[(oc*16+ic)*k + j];
                s  += w * pw[ic];
                sb += w * pb[ic];
            }
            ws[OFF_EW + c*7 + (7-k+j)] = s;
            ebv += sb;
        }
        ws[OFF_EB + c] = ebv;
    }
    if (blockIdx.x == 1 && threadIdx.x < 64) {
        int lane = threadIdx.x;
        int m = lane & 15, qq = lane >> 4;
        unsigned short* frw = (unsigned short*)(ws + OFF_FR);
        // mat0 (K=32): 8 f16/lane
        for (int j = 0; j < 8; ++j) {
            int k = qq*8 + j;
            float s = (k < 16) ? mw[m*48+k] + 0.2f*(mw[m*48+16+k] + mw[m*48+32+k])
                               : 0.8f*mw[m*48+16+(k-16)] + 0.16f*mw[m*48+32+(k-16)];
            _Float16 hi = (_Float16)s;
            _Float16 lo = (_Float16)(s - (float)hi);
            frw[0*512 + lane*8 + j] = __builtin_bit_cast(unsigned short, hi);
            frw[1*512 + lane*8 + j] = __builtin_bit_cast(unsigned short, lo);
        }
        // V2 and rw1 (K=16): 4 f16/lane (16x16x16 A-frag)
        for (int j = 0; j < 4; ++j) {
            int k = qq*4 + j;
            float sv = 0.64f*mw[m*48+32+k];
            float sr = rw1[m*16+k];
            _Float16 vhi = (_Float16)sv;
            _Float16 vlo = (_Float16)(sv - (float)vhi);
            _Float16 rhi = (_Float16)sr;
            _Float16 rlo = (_Float16)(sr - (float)rhi);
            frw[2*512 + lane*4 + j] = __builtin_bit_cast(unsigned short, vhi);
            frw[3*512 + lane*4 + j] = __builtin_bit_cast(unsigned short, vlo);
            frw[4*512 + lane*4 + j] = __builtin_bit_cast(unsigned short, rhi);
            frw[5*512 + lane*4 + j] = __builtin_bit_cast(unsigned short, rlo);
        }
    }
}

// ---------------- graph: 4 nodes/block, shared score loads, LDS-staged scores ----------------
// Each block computes scores for GNPB=4 nodes off the SAME m1T/m2T loads (score traffic
// 295->74 MB), stages them in LDS s[4][1536], then runs the 12 extraction rounds for all
// 4 nodes under shared barriers (26 barriers/block = 6.5/node vs 26/node). No register
// arrays live across barriers (spill rule). Tie-break = lowest index on equal value,
// identical to the 1-node version. Output format unchanged:
// adj[j][v] = {pk_f16(w,w), nb}, j=12 = normalized self-loop.
__global__ __launch_bounds__(256) void graph_kernel(
    const float* __restrict__ m1, const float* __restrict__ m2,
    const float* __restrict__ m1T, const float* __restrict__ m2T,
    int2* __restrict__ adj)
{
    __shared__ float s_lds[GNPB][1536];     // 24576 B
    __shared__ float m1v4[GNPB][16], m2v4[GNPB][16];
    __shared__ float wred_v[GNPB][4];
    __shared__ int   wred_i[GNPB][4];
    __shared__ float winw[GNPB][TOPKK];
    __shared__ int   wini[GNPB][TOPKK];

    const int v0 = blockIdx.x * GNPB;
    const int tid = threadIdx.x;
    const int lane = tid & 63;
    const int wv = tid >> 6;

    if (tid < GNPB*16) {
        int k = tid >> 4, i = tid & 15;
        m1v4[k][i] = m1[(v0+k)*16 + i];
        m2v4[k][i] = m2[(v0+k)*16 + i];
    }
    __syncthreads();

    // score phase: 32 loads per j, reused for 4 nodes
    #pragma unroll
    for (int u = 0; u < 6; ++u) {
        int j = tid + 256*u;
        float d0 = 0.f, d1 = 0.f, d2 = 0.f, d3 = 0.f;
        if (j < NN) {
            #pragma unroll
            for (int i = 0; i < 16; ++i) {
                float a2t = m2T[i*NN+j];
                float a1t = m1T[i*NN+j];
                d0 += m1v4[0][i]*a2t - m2v4[0][i]*a1t;
                d1 += m1v4[1][i]*a2t - m2v4[1][i]*a1t;
                d2 += m1v4[2][i]*a2t - m2v4[2][i]*a1t;
                d3 += m1v4[3][i]*a2t - m2v4[3][i]*a1t;
            }
            float t0 = tanhf(1.5f*d0), t1 = tanhf(1.5f*d1);
            float t2 = tanhf(1.5f*d2), t3 = tanhf(1.5f*d3);
            s_lds[0][j] = t0 > 0.f ? t0 : 0.f;
            s_lds[1][j] = t1 > 0.f ? t1 : 0.f;
            s_lds[2][j] = t2 > 0.f ? t2 : 0.f;
            s_lds[3][j] = t3 > 0.f ? t3 : 0.f;
        } else {
            s_lds[0][j] = -1.f; s_lds[1][j] = -1.f;
            s_lds[2][j] = -1.f; s_lds[3][j] = -1.f;
        }
    }
    __syncthreads();

    for (int it = 0; it < TOPKK; ++it) {
        #pragma unroll
        for (int k = 0; k < GNPB; ++k) {
            float lb = -2.f; int li = 0;
            #pragma unroll
            for (int u = 0; u < 6; ++u) {
                int j = tid + 256*u;
                float val = s_lds[k][j];
                if (val > lb) { lb = val; li = j; }   // ascending j: lowest idx on tie
            }
            #pragma unroll
            for (int off = 32; off > 0; off >>= 1) {
                float ov = __shfl_down(lb, off);
                int   oi = __shfl_down(li, off);
                if (ov > lb || (ov == lb && oi < li)) { lb = ov; li = oi; }
            }
            if (lane == 0) { wred_v[k][wv] = lb; wred_i[k][wv] = li; }
        }
        __syncthreads();
        if (tid < GNPB) {
            int k = tid;
            float bv = wred_v[k][0]; int bi = wred_i[k][0];
            #pragma unroll
            for (int w = 1; w < 4; ++w) {
                float ov = wred_v[k][w]; int oi = wred_i[k][w];
                if (ov > bv || (ov == bv && oi < bi)) { bv = ov; bi = oi; }
            }
            winw[k][it] = bv; wini[k][it] = bi;
            s_lds[k][bi] = -1.f;   // remove winner
        }
        __syncthreads();
    }

    if (tid < GNPB) {
        int k = tid; int v = v0 + k;
        float s = 1.f;
        #pragma unroll
        for (int it = 0; it < TOPKK; ++it) s += winw[k][it];
        float inv = 1.f/s;
        #pragma unroll
        for (int it = 0; it < TOPKK; ++it) {
            float w = winw[k][it]*inv;
            adj[it*NN + v] = make_int2((int)pk2(w, w), wini[k][it]);
        }
        adj[TOPKK*NN + v] = make_int2((int)pk2(inv, inv), v);   // normalized self-loop
    }
}

__device__ __forceinline__ half8 ldfrag(const unsigned short* fr, int plane, int lane) {
    const uint4* p = (const uint4*)(fr + plane*512);
    return as_h8(p[lane]);
}
__device__ __forceinline__ half4v ldfrag4(const unsigned short* fr, int plane, int lane) {
    const uint2* p = (const uint2*)(fr + plane*512);
    return __builtin_bit_cast(half4v, p[lane]);
}

// ---------------- main (= round-6 structure, best verified: 117us) ----------------
// 6-plane LDS (144 KB), 2 barriers/t (merged B2+D via V2·(A·u1)=A·(V2·u1) commute).
// part: per-t packed-f16 RMW (v_pk_add_f16). NO cross-barrier register arrays —
// r1 (zsv[8]) and r8 (rp[6][4]) both scratch-spilled (+170-500MB HBM, 2.7x slower).
// r9 lesson: wave-balanced chunking of conv/B1 does NOT help — per-wave critical
// path is ceil(94/64)=2 gather iterations either way; chunking only added
// half-empty iterations (-7us). Keep tid+NTH*s indexing.
__global__ __launch_bounds__(NTH, 4) void main_kernel(
    const float* __restrict__ x,
    const float* __restrict__ ew, const float* __restrict__ eb,
    const int2* __restrict__ adj,
    const unsigned short* __restrict__ fr,
    unsigned int* __restrict__ part,
    const float* __restrict__ mb, const float* __restrict__ rb1)
{
    __shared__ uint4 feat[6][NPAD];  // 144384 B

    const int tid = threadIdx.x;
    const int lane = tid & 63;
    const int wid = tid >> 6;
    const int b = blockIdx.x >> 5;
    const int g = blockIdx.x & 31;
    const int t0 = (g*TLEN) >> 5;
    const int t1 = ((g+1)*TLEN) >> 5;
    const int n0 = lane & 15, q = lane >> 4;
    unsigned int* partBG = part + (size_t)(b*NG + g)*NN*8;

    // ---- prologue: A(t0) -> planes 0,1 ----
    #pragma unroll 1
    for (int s = 0; s < SN; ++s) {
        int v = tid + NTH*s;
        if (v < NN) {
            float xv[7];
            #pragma unroll
            for (int d = 0; d < 7; ++d) xv[d] = x[(b*TIN + t0 + d)*NN + v];
            float h[16];
            #pragma unroll
            for (int c = 0; c < 16; ++c) {
                float a = eb[c];
                #pragma unroll
                for (int d = 0; d < 7; ++d) a += ew[c*7+d]*xv[d];
                h[c] = a > 0.f ? a : 0.f;
            }
            feat[0][v] = make_uint4(pk2(h[0],h[1]), pk2(h[2],h[3]), pk2(h[4],h[5]), pk2(h[6],h[7]));
            feat[1][v] = make_uint4(pk2(h[8],h[9]), pk2(h[10],h[11]), pk2(h[12],h[13]), pk2(h[14],h[15]));
        }
    }
    __syncthreads();

    for (int t = t0; t < t1; ++t) {
        const int par = (t - t0) & 1;
        const int hc = par ? 4 : 0;   // current h1 planes (hc, hc+1)
        const int hn = par ? 0 : 4;   // next    h1 planes

        // ---- B1: u1 = A@h1 (normalized weights, incl self-loop) -> planes 2,3 (packed f16) ----
        #pragma unroll 1
        for (int s = 0; s < SN; ++s) {
            int v = tid + NTH*s;
            if (v < NN) {
                const half2v zero = {(_Float16)0.f, (_Float16)0.f};
                half2v acc[8];
                #pragma unroll
                for (int i = 0; i < 8; ++i) acc[i] = zero;
                #pragma unroll
                for (int j = 0; j < 13; ++j) {
                    int2 aw = adj[j*NN + v];            // coalesced 8B: {pk_f16(w,w), idx}
                    half2v w2 = as_h2((unsigned int)aw.x);
                    int nb = aw.y;
                    uint4 b0 = feat[hc][nb], b1 = feat[hc+1][nb];
                    acc[0] = as_h2(b0.x) * w2 + acc[0];
                    acc[1] = as_h2(b0.y) * w2 + acc[1];
                    acc[2] = as_h2(b0.z) * w2 + acc[2];
                    acc[3] = as_h2(b0.w) * w2 + acc[3];
                    acc[4] = as_h2(b1.x) * w2 + acc[4];
                    acc[5] = as_h2(b1.y) * w2 + acc[5];
                    acc[6] = as_h2(b1.z) * w2 + acc[6];
                    acc[7] = as_h2(b1.w) * w2 + acc[7];
                }
                feat[2][v] = make_uint4(as_u(acc[0]), as_u(acc[1]), as_u(acc[2]), as_u(acc[3]));
                feat[3][v] = make_uint4(as_u(acc[4]), as_u(acc[5]), as_u(acc[6]), as_u(acc[7]));
            }
        }
        __syncthreads();

        // ---- M (merged): conv(t+1) -> hn planes ; per-tile register pipeline ----
        if (t + 1 < t1) {
            #pragma unroll 1
            for (int s = 0; s < SN; ++s) {
                int v = tid + NTH*s;
                if (v < NN) {
                    float xv[7];
                    #pragma unroll
                    for (int d = 0; d < 7; ++d) xv[d] = x[(b*TIN + (t+1) + d)*NN + v];
                    float h[16];
                    #pragma unroll
                    for (int c = 0; c < 16; ++c) {
                        float a = eb[c];
                        #pragma unroll
                        for (int d = 0; d < 7; ++d) a += ew[c*7+d]*xv[d];
                        h[c] = a > 0.f ? a : 0.f;
                    }
                    feat[hn][v]   = make_uint4(pk2(h[0],h[1]), pk2(h[2],h[3]), pk2(h[4],h[5]), pk2(h[6],h[7]));
                    feat[hn+1][v] = make_uint4(pk2(h[8],h[9]), pk2(h[10],h[11]), pk2(h[12],h[13]), pk2(h[14],h[15]));
                }
            }
        }
        {
            half8  a1h = ldfrag(fr, 0, lane),  a1l = ldfrag(fr, 1, lane);
            half4v v2h = ldfrag4(fr, 2, lane), v2l = ldfrag4(fr, 3, lane);
            half4v r1h = ldfrag4(fr, 4, lane), r1l = ldfrag4(fr, 5, lane);
            float mbq[4], rbq[4];
            #pragma unroll
            for (int r = 0; r < 4; ++r) { mbq[r] = mb[q*4+r]; rbq[r] = rb1[q*4+r]; }
            const uint2* uH = (const uint2*)feat[2 + (q >> 1)];   // u1 half-slots
            #pragma unroll 1
            for (int T = wid; T < NTILE; T += 16) {
                int n = T*16 + n0;
                // z = [W1|U] @ [h1;u1]  (K=32, f32 regs)
                half8 bf = as_h8(feat[(q < 2) ? (hc + q) : q][n]);  // K-quads: h1,h1,u1,u1
                v4f z = {0.f,0.f,0.f,0.f};
                z = __builtin_amdgcn_mfma_f32_16x16x32_f16(a1h, bf, z, 0, 0, 0);
                z = __builtin_amdgcn_mfma_f32_16x16x32_f16(a1l, bf, z, 0, 0, 0);
                // gather (A·u1)[ch q*4..q*4+3][n] -> C-layout == 16x16x16 B-frag layout
                int vc = n < NN ? n : NN-1;   // clamp: keep adj/LDS reads in range
                const half2v zero = {(_Float16)0.f, (_Float16)0.f};
                half2v ga = zero, gb = zero;
                #pragma unroll
                for (int j = 0; j < 13; ++j) {
                    int2 aw = adj[j*NN + vc];
                    half2v w2 = as_h2((unsigned int)aw.x);
                    int nb = aw.y;
                    uint2 ps = uH[nb*2 + (q & 1)];
                    ga = as_h2(ps.x) * w2 + ga;
                    gb = as_h2(ps.y) * w2 + gb;
                }
                half4v w4 = {ga.x, ga.y, gb.x, gb.y};
                // s = V2 @ (A·u1)  (K=16)
                v4f sv = {0.f,0.f,0.f,0.f};
                sv = __builtin_amdgcn_mfma_f32_16x16x16f16(v2h, w4, sv, 0, 0, 0);
                sv = __builtin_amdgcn_mfma_f32_16x16x16f16(v2l, w4, sv, 0, 0, 0);
                // y = relu(mb + z + s) in regs -> already a valid K=16 B-frag
                float y0 = mbq[0] + z[0] + sv[0];
                float y1 = mbq[1] + z[1] + sv[1];
                float y2 = mbq[2] + z[2] + sv[2];
                float y3 = mbq[3] + z[3] + sv[3];
                y0 = y0 > 0.f ? y0 : 0.f;  y1 = y1 > 0.f ? y1 : 0.f;
                y2 = y2 > 0.f ? y2 : 0.f;  y3 = y3 > 0.f ? y3 : 0.f;
                uint2 yk; yk.x = pk2(y0, y1); yk.y = pk2(y2, y3);
                half4v y4 = __builtin_bit_cast(half4v, yk);
                // r = rw1 @ y (K=16)
                v4f acc = {0.f,0.f,0.f,0.f};
                acc = __builtin_amdgcn_mfma_f32_16x16x16f16(r1h, y4, acc, 0, 0, 0);
                acc = __builtin_amdgcn_mfma_f32_16x16x16f16(r1l, y4, acc, 0, 0, 0);
                if (n < NN) {
                    float r0 = acc[0]+rbq[0], r1 = acc[1]+rbq[1], r2 = acc[2]+rbq[2], r3 = acc[3]+rbq[3];
                    r0 = r0 > 0.f ? r0 : 0.f;  r1 = r1 > 0.f ? r1 : 0.f;
                    r2 = r2 > 0.f ? r2 : 0.f;  r3 = r3 > 0.f ? r3 : 0.f;
                    uint2 nv; nv.x = pk2(r0, r1); nv.y = pk2(r2, r3);
                    uint2* pp = (uint2*)(partBG + (size_t)n*8 + q*2);
                    if (t == t0) {
                        *pp = nv;
                    } else {
                        uint2 o = *pp;
                        uint2 m;
                        m.x = as_u(as_h2(o.x) + as_h2(nv.x));   // v_pk_add_f16
                        m.y = as_u(as_h2(o.y) + as_h2(nv.y));
                        *pp = m;
                    }
                }
            }
        }
        __syncthreads();   // next B1 reads hn planes + writes planes 2,3 (read by M)
    }
}

// ---------------- fused reduce: part (packed f16, 32 g) -> mean -> rw2 matvec -> out ----------------
__global__ __launch_bounds__(256) void reduce_kernel(const unsigned int* __restrict__ part,
                                                     const float* __restrict__ rw2,
                                                     const float* __restrict__ rb2,
                                                     float* __restrict__ out)
{
    int idx = blockIdx.x*256 + threadIdx.x;     // over b*NN+v
    if (idx >= BB*NN) return;
    int v = idx % NN;
    int b = idx / NN;
    float s[16];
    #pragma unroll
    for (int c = 0; c < 16; ++c) s[c] = 0.f;
    #pragma unroll 4
    for (int g = 0; g < NG; ++g) {
        const uint4* p4 = (const uint4*)(part + ((size_t)(b*NG + g)*NN + v)*8);
        uint4 u0 = p4[0], u1 = p4[1];
        s[0] += h2lo(u0.x); s[1] += h2hi(u0.x); s[2]  += h2lo(u0.y); s[3]  += h2hi(u0.y);
        s[4] += h2lo(u0.z); s[5] += h2hi(u0.z); s[6]  += h2lo(u0.w); s[7]  += h2hi(u0.w);
        s[8] += h2lo(u1.x); s[9] += h2hi(u1.x); s[10] += h2lo(u1.y); s[11] += h2hi(u1.y);
        s[12]+= h2lo(u1.z); s[13]+= h2hi(u1.z); s[14] += h2lo(u1.w); s[15] += h2hi(u1.w);
    }
    #pragma unroll
    for (int c = 0; c < 16; ++c) s[c] *= (1.0f/TLEN);
    #pragma unroll
    for (int o = 0; o < TOUTC; ++o) {
        float a = rb2[o];
        #pragma unroll
        for (int c = 0; c < 16; ++c) a += rw2[o*16+c]*s[c];
        out[(b*TOUTC + o)*NN + v] = a;
    }
}

extern "C" void kernel_launch(void* const* d_in, const int* in_sizes, int n_in,
                              void* d_out, int out_size, void* d_ws, size_t ws_size,
                              hipStream_t stream)
{
    const float* x   = (const float*)d_in[0];
    const float* pw  = (const float*)d_in[1];
    const float* pb  = (const float*)d_in[2];
    const float* tw2 = (const float*)d_in[3];
    const float* tb2 = (const float*)d_in[4];
    const float* tw3 = (const float*)d_in[5];
    const float* tb3 = (const float*)d_in[6];
    const float* tw6 = (const float*)d_in[7];
    const float* tb6 = (const float*)d_in[8];
    const float* tw7 = (const float*)d_in[9];
    const float* tb7 = (const float*)d_in[10];
    const float* e1  = (const float*)d_in[11];
    const float* e2  = (const float*)d_in[12];
    const float* gw1 = (const float*)d_in[13];
    const float* gb1 = (const float*)d_in[14];
    const float* gw2 = (const float*)d_in[15];
    const float* gb2 = (const float*)d_in[16];
    const float* mw  = (const float*)d_in[17];
    const float* mb  = (const float*)d_in[18];
    const float* rw1 = (const float*)d_in[19];
    const float* rb1 = (const float*)d_in[20];
    const float* rw2 = (const float*)d_in[21];
    const float* rb2 = (const float*)d_in[22];
    float* ws  = (float*)d_ws;
    float* out = (float*)d_out;

    prep_kernel<<<(NN + 255)/256, 256, 0, stream>>>(e1,e2,gw1,gb1,gw2,gb2,pw,pb,
                                                    tw2,tb2,tw3,tb3,tw6,tb6,tw7,tb7,
                                                    mw, rw1, ws);
    graph_kernel<<<(NN + GNPB - 1)/GNPB, 256, 0, stream>>>(ws + OFF_M1, ws + OFF_M2,
                                                           ws + OFF_M1T, ws + OFF_M2T,
                                                           (int2*)(ws + OFF_ADJ));
    main_kernel<<<BB*NG, NTH, 0, stream>>>(x, ws + OFF_EW, ws + OFF_EB,
                                           (const int2*)(ws + OFF_ADJ),
                                           (const unsigned short*)(ws + OFF_FR),
                                           (unsigned int*)(ws + OFF_PART), mb, rb1);
    reduce_kernel<<<(BB*NN + 255)/256, 256, 0, stream>>>((const unsigned int*)(ws + OFF_PART),
                                                         rw2, rb2, out);
}

// Round 11
// 250.767 us; speedup vs baseline: 1.7214x; 1.7214x over previous
//
#include <hip/hip_runtime.h>

#define BB 8
#define TIN 168
#define NN 1500
#define TOUTC 24
#define TLEN 162
#define NG 32
#define NTH 1024
#define SN 2
#define TOPKK 12
#define NTILE 94   // ceil(1504/16)
#define NPAD 1504

// workspace offsets (in 4-byte elements)
#define OFF_M1   0
#define OFF_M2   24000
#define OFF_M1T  48000
#define OFF_M2T  72000
#define OFF_EW   96000
#define OFF_EB   96112
#define OFF_ADJ  96128      // fused transposed adj: int2 [13][NN] = {pk_f16(w,w), idx}
#define OFF_FR   135128     // 6 frag planes x 512 ushorts = 1536 floats
#define OFF_PART 328664     // packed f16: 8*32*1500*8 u32 = 3,072,000
// total ws = 3,400,664 floats = 13.6 MB

typedef __attribute__((ext_vector_type(8))) _Float16 half8;
typedef __attribute__((ext_vector_type(4))) _Float16 half4v;
typedef __attribute__((ext_vector_type(2))) _Float16 half2v;
typedef __attribute__((ext_vector_type(4))) float v4f;

// pack 2 f32 -> packed f16 pair in one v_cvt_pkrtz_f16_f32
__device__ __forceinline__ unsigned int pk2(float lo, float hi) {
    return __builtin_bit_cast(unsigned int, __builtin_amdgcn_cvt_pkrtz(lo, hi));
}
__device__ __forceinline__ float h2lo(unsigned int u) {
    return (float)__builtin_bit_cast(half2v, u).x;
}
__device__ __forceinline__ float h2hi(unsigned int u) {
    return (float)__builtin_bit_cast(half2v, u).y;
}
__device__ __forceinline__ half2v as_h2(unsigned int u) { return __builtin_bit_cast(half2v, u); }
__device__ __forceinline__ unsigned int as_u(half2v h) { return __builtin_bit_cast(unsigned int, h); }
__device__ __forceinline__ half8 as_h8(uint4 u) { return __builtin_bit_cast(half8, u); }

// ---------------- prep: embeddings (16-way parallel) + eff. taps + MFMA weight frags ----------------
// r10 post-mortem: the old 6-block, thread-per-node embedding phase was a ~125-180us
// latency crawl (VALUBusy 0.2%, occupancy 0.27% — 1 wave on 24 of 256 CUs, serial
// dependent loads + 32-reg accumulator arrays + 64-way scattered transpose stores).
// Now: one thread per (n,o) pair — 24000 threads / 94 blocks. Per thread: 2 scalar
// accumulators, 16-step FMA chain; M1/M2 stores idx-linear (coalesced); 2 transpose
// stores/thread. Taps (block 0) and MFMA frags (block 1) unchanged.
__global__ __launch_bounds__(256) void prep_kernel(
    const float* __restrict__ e1, const float* __restrict__ e2,
    const float* __restrict__ gw1, const float* __restrict__ gb1,
    const float* __restrict__ gw2, const float* __restrict__ gb2,
    const float* __restrict__ pw, const float* __restrict__ pb,
    const float* __restrict__ tw2, const float* __restrict__ tb2,
    const float* __restrict__ tw3, const float* __restrict__ tb3,
    const float* __restrict__ tw6, const float* __restrict__ tb6,
    const float* __restrict__ tw7, const float* __restrict__ tb7,
    const float* __restrict__ mw, const float* __restrict__ rw1,
    float* __restrict__ ws)
{
    int idx = blockIdx.x * 256 + threadIdx.x;   // over n*16+o
    int n = idx >> 4, o = idx & 15;
    if (n < NN) {
        float a1 = gb1[o], a2 = gb2[o];
        #pragma unroll
        for (int i = 0; i < 16; ++i) {
            a1 += e1[n*16+i] * gw1[i*16+o];
            a2 += e2[n*16+i] * gw2[i*16+o];
        }
        float t1v = tanhf(1.5f*a1);
        float t2v = tanhf(1.5f*a2);
        ws[OFF_M1 + n*16+o] = t1v;          // idx-linear: coalesced
        ws[OFF_M2 + n*16+o] = t2v;
        ws[OFF_M1T + o*NN + n] = t1v;       // transposed copy for graph reads
        ws[OFF_M2T + o*NN + n] = t2v;
    }
    if (blockIdx.x == 0 && threadIdx.x < 16) {
        int c = threadIdx.x;
        int br = c >> 2, oc = c & 3;
        const float* tw; const float* tb; int k;
        if (br == 0)      { tw = tw2; tb = tb2; k = 2; }
        else if (br == 1) { tw = tw3; tb = tb3; k = 3; }
        else if (br == 2) { tw = tw6; tb = tb6; k = 6; }
        else              { tw = tw7; tb = tb7; k = 7; }
        for (int d = 0; d < 7; ++d) ws[OFF_EW + c*7 + d] = 0.f;
        float ebv = tb[oc];
        for (int j = 0; j < k; ++j) {
            float s = 0.f, sb = 0.f;
            for (int ic = 0; ic < 16; ++ic) {
                float w = tw[(oc*16+ic)*k + j];
                s  += w * pw[ic];
                sb += w * pb[ic];
            }
            ws[OFF_EW + c*7 + (7-k+j)] = s;
            ebv += sb;
        }
        ws[OFF_EB + c] = ebv;
    }
    if (blockIdx.x == 1 && threadIdx.x < 64) {
        int lane = threadIdx.x;
        int m = lane & 15, qq = lane >> 4;
        unsigned short* frw = (unsigned short*)(ws + OFF_FR);
        // mat0 = [W1|U] (K=32): 8 f16/lane, hi/lo split
        for (int j = 0; j < 8; ++j) {
            int k = qq*8 + j;
            float s = (k < 16) ? mw[m*48+k] + 0.2f*(mw[m*48+16+k] + mw[m*48+32+k])
                               : 0.8f*mw[m*48+16+(k-16)] + 0.16f*mw[m*48+32+(k-16)];
            _Float16 hi = (_Float16)s;
            _Float16 lo = (_Float16)(s - (float)hi);
            frw[0*512 + lane*8 + j] = __builtin_bit_cast(unsigned short, hi);
            frw[1*512 + lane*8 + j] = __builtin_bit_cast(unsigned short, lo);
        }
        // V2 = 0.64*M2 and rw1 (K=16): 4 f16/lane (16x16x16 A-frag), hi/lo split
        for (int j = 0; j < 4; ++j) {
            int k = qq*4 + j;
            float sv = 0.64f*mw[m*48+32+k];
            float sr = rw1[m*16+k];
            _Float16 vhi = (_Float16)sv;
            _Float16 vlo = (_Float16)(sv - (float)vhi);
            _Float16 rhi = (_Float16)sr;
            _Float16 rlo = (_Float16)(sr - (float)rhi);
            frw[2*512 + lane*4 + j] = __builtin_bit_cast(unsigned short, vhi);
            frw[3*512 + lane*4 + j] = __builtin_bit_cast(unsigned short, vlo);
            frw[4*512 + lane*4 + j] = __builtin_bit_cast(unsigned short, rhi);
            frw[5*512 + lane*4 + j] = __builtin_bit_cast(unsigned short, rlo);
        }
    }
}

// ---------------- graph (r9 version, proven): coalesced transposed score loads + shuffle-argmax ----------------
// Output: fused TRANSPOSED adjacency adj[j][v] = {pk_f16(w,w), nb}, j=12 = normalized self-loop.
__global__ __launch_bounds__(256) void graph_kernel(
    const float* __restrict__ m1, const float* __restrict__ m2,
    const float* __restrict__ m1T, const float* __restrict__ m2T,
    int2* __restrict__ adj)
{
    int v = blockIdx.x;
    int tid = threadIdx.x;
    __shared__ float wv4[4];
    __shared__ int   wi4[4];
    __shared__ int   bcast_i;
    __shared__ float m1v[16], m2v[16];
    if (tid < 16) { m1v[tid] = m1[v*16+tid]; m2v[tid] = m2[v*16+tid]; }
    __syncthreads();
    float sreg[6];
    #pragma unroll
    for (int u = 0; u < 6; ++u) {
        int j = tid + 256*u;
        float a = -1.f;
        if (j < NN) {
            float d = 0.f;
            #pragma unroll
            for (int i = 0; i < 16; ++i)
                d += m1v[i]*m2T[i*NN+j] - m2v[i]*m1T[i*NN+j];   // lane-consecutive j: full lines
            float t = tanhf(1.5f*d);
            a = t > 0.f ? t : 0.f;
        }
        sreg[u] = a;
    }
    float lb = -1.f; int li = NN;
    #pragma unroll
    for (int u = 0; u < 6; ++u) {
        int j = tid + 256*u;
        if (j < NN && sreg[u] > lb) { lb = sreg[u]; li = j; }
    }
    const int wid = tid >> 6;
    float kw[TOPKK]; int ki[TOPKK];   // tid0-only, statically indexed -> registers
    #pragma unroll
    for (int it = 0; it < TOPKK; ++it) {
        float bv = lb; int bi = li;
        #pragma unroll
        for (int off = 32; off > 0; off >>= 1) {
            float ov = __shfl_down(bv, off);
            int   oi = __shfl_down(bi, off);
            if (ov > bv || (ov == bv && oi < bi)) { bv = ov; bi = oi; }
        }
        if ((tid & 63) == 0) { wv4[wid] = bv; wi4[wid] = bi; }
        __syncthreads();
        if (tid == 0) {
            #pragma unroll
            for (int w = 1; w < 4; ++w) {
                float ov = wv4[w]; int oi = wi4[w];
                if (ov > bv || (ov == bv && oi < bi)) { bv = ov; bi = oi; }
            }
            kw[it] = bv; ki[it] = bi;
            bcast_i = bi;
        }
        __syncthreads();
        int win = bcast_i;
        if (li == win) {
            #pragma unroll
            for (int u = 0; u < 6; ++u)
                if (tid + 256*u == win) sreg[u] = -1.f;
            lb = -1.f; li = NN;
            #pragma unroll
            for (int u = 0; u < 6; ++u) {
                int j = tid + 256*u;
                if (j < NN && sreg[u] > lb) { lb = sreg[u]; li = j; }
            }
        }
    }
    if (tid == 0) {
        float s = 1.f;
        #pragma unroll
        for (int it = 0; it < TOPKK; ++it) s += kw[it];
        float inv = 1.f/s;
        #pragma unroll
        for (int it = 0; it < TOPKK; ++it) {
            float w = kw[it]*inv;
            adj[it*NN + v] = make_int2((int)pk2(w, w), ki[it]);
        }
        adj[TOPKK*NN + v] = make_int2((int)pk2(inv, inv), v);   // normalized self-loop
    }
}

__device__ __forceinline__ half8 ldfrag(const unsigned short* fr, int plane, int lane) {
    const uint4* p = (const uint4*)(fr + plane*512);
    return as_h8(p[lane]);
}
__device__ __forceinline__ half4v ldfrag4(const unsigned short* fr, int plane, int lane) {
    const uint2* p = (const uint2*)(fr + plane*512);
    return __builtin_bit_cast(half4v, p[lane]);
}

// ---------------- main (= round-6/9 structure, best verified) ----------------
// 6-plane LDS (144 KB), 2 barriers/t (merged B2+D via V2·(A·u1)=A·(V2·u1) commute).
// part: per-t packed-f16 RMW (v_pk_add_f16). NO cross-barrier register arrays —
// r1 (zsv[8]) and r8 (rp[6][4]) both scratch-spilled (+170-500MB HBM, 2.7x slower).
// r9 lesson: wave-balanced chunking of conv/B1 does NOT help (ceil(94/64)=2 either way).
__global__ __launch_bounds__(NTH, 4) void main_kernel(
    const float* __restrict__ x,
    const float* __restrict__ ew, const float* __restrict__ eb,
    const int2* __restrict__ adj,
    const unsigned short* __restrict__ fr,
    unsigned int* __restrict__ part,
    const float* __restrict__ mb, const float* __restrict__ rb1)
{
    __shared__ uint4 feat[6][NPAD];  // 144384 B

    const int tid = threadIdx.x;
    const int lane = tid & 63;
    const int wid = tid >> 6;
    const int b = blockIdx.x >> 5;
    const int g = blockIdx.x & 31;
    const int t0 = (g*TLEN) >> 5;
    const int t1 = ((g+1)*TLEN) >> 5;
    const int n0 = lane & 15, q = lane >> 4;
    unsigned int* partBG = part + (size_t)(b*NG + g)*NN*8;

    // ---- prologue: A(t0) -> planes 0,1 ----
    #pragma unroll 1
    for (int s = 0; s < SN; ++s) {
        int v = tid + NTH*s;
        if (v < NN) {
            float xv[7];
            #pragma unroll
            for (int d = 0; d < 7; ++d) xv[d] = x[(b*TIN + t0 + d)*NN + v];
            float h[16];
            #pragma unroll
            for (int c = 0; c < 16; ++c) {
                float a = eb[c];
                #pragma unroll
                for (int d = 0; d < 7; ++d) a += ew[c*7+d]*xv[d];
                h[c] = a > 0.f ? a : 0.f;
            }
            feat[0][v] = make_uint4(pk2(h[0],h[1]), pk2(h[2],h[3]), pk2(h[4],h[5]), pk2(h[6],h[7]));
            feat[1][v] = make_uint4(pk2(h[8],h[9]), pk2(h[10],h[11]), pk2(h[12],h[13]), pk2(h[14],h[15]));
        }
    }
    __syncthreads();

    for (int t = t0; t < t1; ++t) {
        const int par = (t - t0) & 1;
        const int hc = par ? 4 : 0;   // current h1 planes (hc, hc+1)
        const int hn = par ? 0 : 4;   // next    h1 planes

        // ---- B1: u1 = A@h1 (normalized weights, incl self-loop) -> planes 2,3 (packed f16) ----
        #pragma unroll 1
        for (int s = 0; s < SN; ++s) {
            int v = tid + NTH*s;
            if (v < NN) {
                const half2v zero = {(_Float16)0.f, (_Float16)0.f};
                half2v acc[8];
                #pragma unroll
                for (int i = 0; i < 8; ++i) acc[i] = zero;
                #pragma unroll
                for (int j = 0; j < 13; ++j) {
                    int2 aw = adj[j*NN + v];            // coalesced 8B: {pk_f16(w,w), idx}
                    half2v w2 = as_h2((unsigned int)aw.x);
                    int nb = aw.y;
                    uint4 b0 = feat[hc][nb], b1 = feat[hc+1][nb];
                    acc[0] = as_h2(b0.x) * w2 + acc[0];
                    acc[1] = as_h2(b0.y) * w2 + acc[1];
                    acc[2] = as_h2(b0.z) * w2 + acc[2];
                    acc[3] = as_h2(b0.w) * w2 + acc[3];
                    acc[4] = as_h2(b1.x) * w2 + acc[4];
                    acc[5] = as_h2(b1.y) * w2 + acc[5];
                    acc[6] = as_h2(b1.z) * w2 + acc[6];
                    acc[7] = as_h2(b1.w) * w2 + acc[7];
                }
                feat[2][v] = make_uint4(as_u(acc[0]), as_u(acc[1]), as_u(acc[2]), as_u(acc[3]));
                feat[3][v] = make_uint4(as_u(acc[4]), as_u(acc[5]), as_u(acc[6]), as_u(acc[7]));
            }
        }
        __syncthreads();

        // ---- M (merged): conv(t+1) -> hn planes ; per-tile register pipeline ----
        if (t + 1 < t1) {
            #pragma unroll 1
            for (int s = 0; s < SN; ++s) {
                int v = tid + NTH*s;
                if (v < NN) {
                    float xv[7];
                    #pragma unroll
                    for (int d = 0; d < 7; ++d) xv[d] = x[(b*TIN + (t+1) + d)*NN + v];
                    float h[16];
                    #pragma unroll
                    for (int c = 0; c < 16; ++c) {
                        float a = eb[c];
                        #pragma unroll
                        for (int d = 0; d < 7; ++d) a += ew[c*7+d]*xv[d];
                        h[c] = a > 0.f ? a : 0.f;
                    }
                    feat[hn][v]   = make_uint4(pk2(h[0],h[1]), pk2(h[2],h[3]), pk2(h[4],h[5]), pk2(h[6],h[7]));
                    feat[hn+1][v] = make_uint4(pk2(h[8],h[9]), pk2(h[10],h[11]), pk2(h[12],h[13]), pk2(h[14],h[15]));
                }
            }
        }
        {
            half8  a1h = ldfrag(fr, 0, lane),  a1l = ldfrag(fr, 1, lane);
            half4v v2h = ldfrag4(fr, 2, lane), v2l = ldfrag4(fr, 3, lane);
            half4v r1h = ldfrag4(fr, 4, lane), r1l = ldfrag4(fr, 5, lane);
            float mbq[4], rbq[4];
            #pragma unroll
            for (int r = 0; r < 4; ++r) { mbq[r] = mb[q*4+r]; rbq[r] = rb1[q*4+r]; }
            const uint2* uH = (const uint2*)feat[2 + (q >> 1)];   // u1 half-slots
            #pragma unroll 1
            for (int T = wid; T < NTILE; T += 16) {
                int n = T*16 + n0;
                // z = [W1|U] @ [h1;u1]  (K=32, f32 regs)
                half8 bf = as_h8(feat[(q < 2) ? (hc + q) : q][n]);  // K-quads: h1,h1,u1,u1
                v4f z = {0.f,0.f,0.f,0.f};
                z = __builtin_amdgcn_mfma_f32_16x16x32_f16(a1h, bf, z, 0, 0, 0);
                z = __builtin_amdgcn_mfma_f32_16x16x32_f16(a1l, bf, z, 0, 0, 0);
                // gather (A·u1)[ch q*4..q*4+3][n] -> C-layout == 16x16x16 B-frag layout
                int vc = n < NN ? n : NN-1;   // clamp: keep adj/LDS reads in range
                const half2v zero = {(_Float16)0.f, (_Float16)0.f};
                half2v ga = zero, gb = zero;
                #pragma unroll
                for (int j = 0; j < 13; ++j) {
                    int2 aw = adj[j*NN + vc];
                    half2v w2 = as_h2((unsigned int)aw.x);
                    int nb = aw.y;
                    uint2 ps = uH[nb*2 + (q & 1)];
                    ga = as_h2(ps.x) * w2 + ga;
                    gb = as_h2(ps.y) * w2 + gb;
                }
                half4v w4 = {ga.x, ga.y, gb.x, gb.y};
                // s = V2 @ (A·u1)  (K=16)
                v4f sv = {0.f,0.f,0.f,0.f};
                sv = __builtin_amdgcn_mfma_f32_16x16x16f16(v2h, w4, sv, 0, 0, 0);
                sv = __builtin_amdgcn_mfma_f32_16x16x16f16(v2l, w4, sv, 0, 0, 0);
                // y = relu(mb + z + s) in regs -> already a valid K=16 B-frag
                float y0 = mbq[0] + z[0] + sv[0];
                float y1 = mbq[1] + z[1] + sv[1];
                float y2 = mbq[2] + z[2] + sv[2];
                float y3 = mbq[3] + z[3] + sv[3];
                y0 = y0 > 0.f ? y0 : 0.f;  y1 = y1 > 0.f ? y1 : 0.f;
                y2 = y2 > 0.f ? y2 : 0.f;  y3 = y3 > 0.f ? y3 : 0.f;
                uint2 yk; yk.x = pk2(y0, y1); yk.y = pk2(y2, y3);
                half4v y4 = __builtin_bit_cast(half4v, yk);
                // r = rw1 @ y (K=16)
                v4f acc = {0.f,0.f,0.f,0.f};
                acc = __builtin_amdgcn_mfma_f32_16x16x16f16(r1h, y4, acc, 0, 0, 0);
                acc = __builtin_amdgcn_mfma_f32_16x16x16f16(r1l, y4, acc, 0, 0, 0);
                if (n < NN) {
                    float r0 = acc[0]+rbq[0], r1 = acc[1]+rbq[1], r2 = acc[2]+rbq[2], r3 = acc[3]+rbq[3];
                    r0 = r0 > 0.f ? r0 : 0.f;  r1 = r1 > 0.f ? r1 : 0.f;
                    r2 = r2 > 0.f ? r2 : 0.f;  r3 = r3 > 0.f ? r3 : 0.f;
                    uint2 nv; nv.x = pk2(r0, r1); nv.y = pk2(r2, r3);
                    uint2* pp = (uint2*)(partBG + (size_t)n*8 + q*2);
                    if (t == t0) {
                        *pp = nv;
                    } else {
                        uint2 o = *pp;
                        uint2 m;
                        m.x = as_u(as_h2(o.x) + as_h2(nv.x));   // v_pk_add_f16
                        m.y = as_u(as_h2(o.y) + as_h2(nv.y));
                        *pp = m;
                    }
                }
            }
        }
        __syncthreads();   // next B1 reads hn planes + writes planes 2,3 (read by M)
    }
}

// ---------------- fused reduce: part (packed f16, 32 g) -> mean -> rw2 matvec -> out ----------------
__global__ __launch_bounds__(256) void reduce_kernel(const unsigned int* __restrict__ part,
                                                     const float* __restrict__ rw2,
                                                     const float* __restrict__ rb2,
                                                     float* __restrict__ out)
{
    int idx = blockIdx.x*256 + threadIdx.x;     // over b*NN+v
    if (idx >= BB*NN) return;
    int v = idx % NN;
    int b = idx / NN;
    float s[16];
    #pragma unroll
    for (int c = 0; c < 16; ++c) s[c] = 0.f;
    #pragma unroll 4
    for (int g = 0; g < NG; ++g) {
        const uint4* p4 = (const uint4*)(part + ((size_t)(b*NG + g)*NN + v)*8);
        uint4 u0 = p4[0], u1 = p4[1];
        s[0] += h2lo(u0.x); s[1] += h2hi(u0.x); s[2]  += h2lo(u0.y); s[3]  += h2hi(u0.y);
        s[4] += h2lo(u0.z); s[5] += h2hi(u0.z); s[6]  += h2lo(u0.w); s[7]  += h2hi(u0.w);
        s[8] += h2lo(u1.x); s[9] += h2hi(u1.x); s[10] += h2lo(u1.y); s[11] += h2hi(u1.y);
        s[12]+= h2lo(u1.z); s[13]+= h2hi(u1.z); s[14] += h2lo(u1.w); s[15] += h2hi(u1.w);
    }
    #pragma unroll
    for (int c = 0; c < 16; ++c) s[c] *= (1.0f/TLEN);
    #pragma unroll
    for (int o = 0; o < TOUTC; ++o) {
        float a = rb2[o];
        #pragma unroll
        for (int c = 0; c < 16; ++c) a += rw2[o*16+c]*s[c];
        out[(b*TOUTC + o)*NN + v] = a;
    }
}

extern "C" void kernel_launch(void* const* d_in, const int* in_sizes, int n_in,
                              void* d_out, int out_size, void* d_ws, size_t ws_size,
                              hipStream_t stream)
{
    const float* x   = (const float*)d_in[0];
    const float* pw  = (const float*)d_in[1];
    const float* pb  = (const float*)d_in[2];
    const float* tw2 = (const float*)d_in[3];
    const float* tb2 = (const float*)d_in[4];
    const float* tw3 = (const float*)d_in[5];
    const float* tb3 = (const float*)d_in[6];
    const float* tw6 = (const float*)d_in[7];
    const float* tb6 = (const float*)d_in[8];
    const float* tw7 = (const float*)d_in[9];
    const float* tb7 = (const float*)d_in[10];
    const float* e1  = (const float*)d_in[11];
    const float* e2  = (const float*)d_in[12];
    const float* gw1 = (const float*)d_in[13];
    const float* gb1 = (const float*)d_in[14];
    const float* gw2 = (const float*)d_in[15];
    const float* gb2 = (const float*)d_in[16];
    const float* mw  = (const float*)d_in[17];
    const float* mb  = (const float*)d_in[18];
    const float* rw1 = (const float*)d_in[19];
    const float* rb1 = (const float*)d_in[20];
    const float* rw2 = (const float*)d_in[21];
    const float* rb2 = (const float*)d_in[22];
    float* ws  = (float*)d_ws;
    float* out = (float*)d_out;

    prep_kernel<<<(NN*16 + 255)/256, 256, 0, stream>>>(e1,e2,gw1,gb1,gw2,gb2,pw,pb,
                                                       tw2,tb2,tw3,tb3,tw6,tb6,tw7,tb7,
                                                       mw, rw1, ws);
    graph_kernel<<<NN, 256, 0, stream>>>(ws + OFF_M1, ws + OFF_M2,
                                         ws + OFF_M1T, ws + OFF_M2T,
                                         (int2*)(ws + OFF_ADJ));
    main_kernel<<<BB*NG, NTH, 0, stream>>>(x, ws + OFF_EW, ws + OFF_EB,
                                           (const int2*)(ws + OFF_ADJ),
                                           (const unsigned short*)(ws + OFF_FR),
                                           (unsigned int*)(ws + OFF_PART), mb, rb1);
    reduce_kernel<<<(BB*NN + 255)/256, 256, 0, stream>>>((const unsigned int*)(ws + OFF_PART),
                                                         rw2, rb2, out);
}